// Round 5
// baseline (2395.723 us; speedup 1.0000x reference)
//
#include <hip/hip_runtime.h>

#define N_NODES 20000
#define S_COLS  4096
#define E_EDGES 640000
#define D_DIM   256

typedef unsigned short bf16_t;
typedef __attribute__((ext_vector_type(8))) short short8;
typedef __attribute__((ext_vector_type(4))) float f32x4;

__device__ __forceinline__ float bf2f(bf16_t u) {
    union { unsigned int i; float f; } v; v.i = ((unsigned int)u) << 16; return v.f;
}
__device__ __forceinline__ bf16_t f2bf(float x) {   // round-to-nearest-even
    union { float f; unsigned int i; } v; v.f = x;
    unsigned int r = v.i + 0x7FFF + ((v.i >> 16) & 1);
    return (bf16_t)(r >> 16);
}
__device__ __forceinline__ float lo_bf(unsigned int u) {
    union { unsigned int i; float f; } v; v.i = u << 16; return v.f;
}
__device__ __forceinline__ float hi_bf(unsigned int u) {
    union { unsigned int i; float f; } v; v.i = u & 0xFFFF0000u; return v.f;
}
__device__ __forceinline__ unsigned int pack_bf(float a, float b) {
    return (unsigned int)f2bf(a) | ((unsigned int)f2bf(b) << 16);
}

// ---------------------------------------------------------------------------
// K1: h0[i] = (cnt*b2 + fsum @ w2) / max(cnt,1). One WAVE per row,
// grid-stride; no LDS atomics, no per-row barriers. w2 LDS tile loaded once
// per block (amortized over ~16 rows/wave).
// ---------------------------------------------------------------------------
__global__ void h0_kernel(const float* __restrict__ init_m,
                          const float* __restrict__ w1, const float* __restrict__ b1,
                          const float* __restrict__ w2, const float* __restrict__ b2,
                          bf16_t* __restrict__ h) {
    __shared__ float w2s[16][256];
    int t    = threadIdx.x;
    int lane = t & 63;
    int wave = t >> 6;

#pragma unroll
    for (int k = 0; k < 16; ++k) w2s[k][t] = w2[k * D_DIM + t];
    __syncthreads();

    float lw1[16], lb1[16];
#pragma unroll
    for (int k = 0; k < 16; ++k) { lw1[k] = w1[k]; lb1[k] = b1[k]; }
    float4 b2v = ((const float4*)b2)[lane];

    int wid    = blockIdx.x * 4 + wave;
    int stride = gridDim.x * 4;
    for (int i = wid; i < N_NODES; i += stride) {
        const float4* rowp = (const float4*)(init_m + (size_t)i * S_COLS);
        float f[16] = {};
        float fc = 0.f;
#pragma unroll
        for (int p = 0; p < 16; ++p) {
            int v4 = lane + p * 64;          // coalesced across lanes
            float4 v = rowp[v4];
            float jb = (float)(v4 * 4);
            if (v.x != 0.f) { fc += 1.f;
#pragma unroll
                for (int k = 0; k < 16; ++k) f[k] += fmaxf(jb * lw1[k] + lb1[k], 0.f); }
            if (v.y != 0.f) { fc += 1.f; float jf = jb + 1.f;
#pragma unroll
                for (int k = 0; k < 16; ++k) f[k] += fmaxf(jf * lw1[k] + lb1[k], 0.f); }
            if (v.z != 0.f) { fc += 1.f; float jf = jb + 2.f;
#pragma unroll
                for (int k = 0; k < 16; ++k) f[k] += fmaxf(jf * lw1[k] + lb1[k], 0.f); }
            if (v.w != 0.f) { fc += 1.f; float jf = jb + 3.f;
#pragma unroll
                for (int k = 0; k < 16; ++k) f[k] += fmaxf(jf * lw1[k] + lb1[k], 0.f); }
        }
        // butterfly-reduce f[16] + fc across the wave
#pragma unroll
        for (int off = 32; off > 0; off >>= 1) {
            fc += __shfl_xor(fc, off, 64);
#pragma unroll
            for (int k = 0; k < 16; ++k) f[k] += __shfl_xor(f[k], off, 64);
        }
        // matvec: lane covers channels lane*4..+3
        float4 acc = { fc * b2v.x, fc * b2v.y, fc * b2v.z, fc * b2v.w };
#pragma unroll
        for (int k = 0; k < 16; ++k) {
            float4 wv = ((const float4*)&w2s[k][0])[lane];
            acc.x += f[k] * wv.x;  acc.y += f[k] * wv.y;
            acc.z += f[k] * wv.z;  acc.w += f[k] * wv.w;
        }
        float inv = 1.f / fmaxf(fc, 1.f);
        ushort4 o;
        o.x = f2bf(acc.x * inv);  o.y = f2bf(acc.y * inv);
        o.z = f2bf(acc.z * inv);  o.w = f2bf(acc.w * inv);
        ((ushort4*)(h + (size_t)i * D_DIM))[lane] = o;
    }
}

// ---------------------------------------------------------------------------
// CSC build (counting sort by destination col)
// ---------------------------------------------------------------------------
__global__ void count_kernel(const int* __restrict__ eidx, int* __restrict__ cnt) {
    int e = blockIdx.x * 256 + threadIdx.x;
    if (e < E_EDGES) atomicAdd(&cnt[eidx[E_EDGES + e]], 1);
}

__global__ void scan_kernel(const int* __restrict__ cnt, int* __restrict__ offs,
                            int* __restrict__ cur) {
    __shared__ int sdata[1024];
    int t = threadIdx.x;
    int base = t * 20;
    int vals[20];
    int local = 0;
#pragma unroll
    for (int k = 0; k < 20; ++k) {
        int idx = base + k;
        int v = (idx < N_NODES) ? cnt[idx] : 0;
        vals[k] = local;
        local += v;
    }
    sdata[t] = local;
    __syncthreads();
    for (int off = 1; off < 1024; off <<= 1) {
        int v = (t >= off) ? sdata[t - off] : 0;
        __syncthreads();
        sdata[t] += v;
        __syncthreads();
    }
    int prefix = (t == 0) ? 0 : sdata[t - 1];
#pragma unroll
    for (int k = 0; k < 20; ++k) {
        int idx = base + k;
        if (idx < N_NODES) {
            int o = prefix + vals[k];
            offs[idx] = o;
            cur[idx]  = o;
        }
    }
    if (t == 1023) offs[N_NODES] = sdata[1023];
}

__global__ void fill_kernel(const int* __restrict__ eidx, const float* __restrict__ attr,
                            int* __restrict__ cur, int* __restrict__ src_s,
                            float* __restrict__ attr_s) {
    int e = blockIdx.x * 256 + threadIdx.x;
    if (e < E_EDGES) {
        int r = eidx[e];
        int c = eidx[E_EDGES + e];
        int pos = atomicAdd(&cur[c], 1);
        src_s[pos]  = r;
        attr_s[pos] = attr[e];
    }
}

// ---------------------------------------------------------------------------
// W preprocessing: transpose + fp32 -> bf16 hi/lo split
// ---------------------------------------------------------------------------
__global__ void wsplit_kernel(const float* __restrict__ W,
                              bf16_t* __restrict__ Wt_hi, bf16_t* __restrict__ Wt_lo) {
    int k = blockIdx.x;
    int n = threadIdx.x;
    float w = W[k * D_DIM + n];
    bf16_t hi = f2bf(w);
    bf16_t lo = f2bf(w - bf2f(hi));
    Wt_hi[n * D_DIM + k] = hi;
    Wt_lo[n * D_DIM + k] = lo;
}

// ---------------------------------------------------------------------------
// K3: t = h @ W, bf16 in/out, W = hi+lo planes (n-major). MFMA 16x16x32.
// ---------------------------------------------------------------------------
__global__ void gemm_mfma_kernel(const bf16_t* __restrict__ h,
                                 const bf16_t* __restrict__ Wt_hi,
                                 const bf16_t* __restrict__ Wt_lo,
                                 bf16_t* __restrict__ t) {
    int w    = threadIdx.x >> 6;
    int lane = threadIdx.x & 63;
    int quad = lane >> 4;
    int id16 = lane & 15;
    int bm   = blockIdx.x * 64 + w * 16;
    int bn   = blockIdx.y * 64;

    f32x4 acc[4];
#pragma unroll
    for (int nt = 0; nt < 4; ++nt) acc[nt] = (f32x4){0.f, 0.f, 0.f, 0.f};

    const bf16_t* arow = h + (size_t)(bm + id16) * D_DIM;
#pragma unroll
    for (int k0 = 0; k0 < 256; k0 += 32) {
        short8 a = *(const short8*)(arow + k0 + quad * 8);
#pragma unroll
        for (int nt = 0; nt < 4; ++nt) {
            const bf16_t* brow = Wt_hi + (size_t)(bn + nt * 16 + id16) * D_DIM + k0 + quad * 8;
            const bf16_t* lrow = Wt_lo + (size_t)(bn + nt * 16 + id16) * D_DIM + k0 + quad * 8;
            short8 bh = *(const short8*)brow;
            short8 bl = *(const short8*)lrow;
            acc[nt] = __builtin_amdgcn_mfma_f32_16x16x32_bf16(a, bh, acc[nt], 0, 0, 0);
            acc[nt] = __builtin_amdgcn_mfma_f32_16x16x32_bf16(a, bl, acc[nt], 0, 0, 0);
        }
    }
#pragma unroll
    for (int nt = 0; nt < 4; ++nt) {
#pragma unroll
        for (int r = 0; r < 4; ++r) {
            int m = bm + quad * 4 + r;
            if (m < N_NODES)
                t[(size_t)m * D_DIM + bn + nt * 16 + id16] = f2bf(acc[nt][r]);
        }
    }
}

// ---------------------------------------------------------------------------
// K2: h_next[c] = relu( sum_{e into c} t[src[e]] * attr[e] )
// One wave per dest; half-wave per edge, 16B loads. Inner loop padded to a
// multiple of 8 edges and unrolled x4 -> 4 loads in flight (padded slots
// have a=0, r=0: row-0 loads, L1-hit, zero contribution).
// ---------------------------------------------------------------------------
__global__ void gather_relu_kernel(const bf16_t* __restrict__ t,
                                   const int* __restrict__ offs,
                                   const int* __restrict__ src_s,
                                   const float* __restrict__ attr_s,
                                   bf16_t* __restrict__ hdst, float* __restrict__ fdst) {
    int wid  = (blockIdx.x * blockDim.x + threadIdx.x) >> 6;
    int lane = threadIdx.x & 63;
    if (wid >= N_NODES) return;
    int half = lane >> 5;
    int l32  = lane & 31;
    int e0 = offs[wid], e1 = offs[wid + 1];

    float acc[8] = {};
    for (int base = e0; base < e1; base += 64) {
        int n = e1 - base; if (n > 64) n = 64;
        int   r_l = 0; float a_l = 0.f;
        if (lane < n) { r_l = src_s[base + lane]; a_l = attr_s[base + lane]; }
        int nn = (n + 7) & ~7;              // pad to 4 pair-iterations
        for (int q = 0; q < nn; q += 8) {
#pragma unroll
            for (int u = 0; u < 4; ++u) {
                int   sl = q + 2 * u + half;
                int   r  = __shfl(r_l, sl, 64);
                float a  = __shfl(a_l, sl, 64);
                uint4 v  = ((const uint4*)(t + (size_t)r * D_DIM))[l32];
                acc[0] += lo_bf(v.x) * a;  acc[1] += hi_bf(v.x) * a;
                acc[2] += lo_bf(v.y) * a;  acc[3] += hi_bf(v.y) * a;
                acc[4] += lo_bf(v.z) * a;  acc[5] += hi_bf(v.z) * a;
                acc[6] += lo_bf(v.w) * a;  acc[7] += hi_bf(v.w) * a;
            }
        }
    }
#pragma unroll
    for (int i = 0; i < 8; ++i) acc[i] += __shfl_xor(acc[i], 32, 64);

    if (half == 0) {
#pragma unroll
        for (int i = 0; i < 8; ++i) acc[i] = fmaxf(acc[i], 0.f);
        if (hdst) {
            uint4 o;
            o.x = pack_bf(acc[0], acc[1]);
            o.y = pack_bf(acc[2], acc[3]);
            o.z = pack_bf(acc[4], acc[5]);
            o.w = pack_bf(acc[6], acc[7]);
            ((uint4*)(hdst + (size_t)wid * D_DIM))[l32] = o;
        } else {
            float4 o0 = { acc[0], acc[1], acc[2], acc[3] };
            float4 o1 = { acc[4], acc[5], acc[6], acc[7] };
            float* dst = fdst + (size_t)wid * D_DIM + l32 * 8;
            *(float4*)dst       = o0;
            *(float4*)(dst + 4) = o1;
        }
    }
}

extern "C" void kernel_launch(void* const* d_in, const int* in_sizes, int n_in,
                              void* d_out, int out_size, void* d_ws, size_t ws_size,
                              hipStream_t stream) {
    const float* init_m = (const float*)d_in[0];
    const int*   eidx   = (const int*)  d_in[1];
    const float* attr   = (const float*)d_in[2];
    const float* w1     = (const float*)d_in[3];
    const float* b1     = (const float*)d_in[4];
    const float* w2     = (const float*)d_in[5];
    const float* b2     = (const float*)d_in[6];
    const float* Wm     = (const float*)d_in[7];
    float* out = (float*)d_out;

    // Workspace layout (bytes). hbuf/tbuf have 16KB slack for the GEMM
    // m-overread (rows 20000..20031; poison is finite bf16).
    char* ws = (char*)d_ws;
    bf16_t* hbuf   = (bf16_t*)ws;                        // 10,240,000 (+16K slack)
    bf16_t* tbuf   = (bf16_t*)(ws + 10256384);           // 10,240,000 (+16K slack)
    bf16_t* Wt_hi  = (bf16_t*)(ws + 20512768);           // 131,072
    bf16_t* Wt_lo  = (bf16_t*)(ws + 20643840);           // 131,072
    int*    cnt    = (int*)   (ws + 20774912);           // 80,000
    int*    offs   = (int*)   (ws + 20854912);           // 80,004
    int*    cur    = (int*)   (ws + 20934928);           // 80,000
    int*    src_s  = (int*)   (ws + 21014928);           // 2,560,000
    float*  attr_s = (float*) (ws + 23574928);           // 2,560,000

    // --- CSC build ---
    hipMemsetAsync(cnt, 0, (size_t)N_NODES * sizeof(int), stream);
    count_kernel<<<(E_EDGES + 255) / 256, 256, 0, stream>>>(eidx, cnt);
    scan_kernel<<<1, 1024, 0, stream>>>(cnt, offs, cur);
    fill_kernel<<<(E_EDGES + 255) / 256, 256, 0, stream>>>(eidx, attr, cur, src_s, attr_s);

    // --- W transpose + hi/lo split ---
    wsplit_kernel<<<D_DIM, D_DIM, 0, stream>>>(Wm, Wt_hi, Wt_lo);

    // --- Projection: wave-per-row, grid-stride ---
    h0_kernel<<<1280, 256, 0, stream>>>(init_m, w1, b1, w2, b2, hbuf);

    // --- 3x GCN layer: t = h@W (MFMA), then h' = relu(gather(t)) ---
    dim3 ggrid((N_NODES * 64 + 255) / 256);
    dim3 mgrid((N_NODES + 63) / 64, 4);
    for (int it = 0; it < 3; ++it) {
        gemm_mfma_kernel<<<mgrid, 256, 0, stream>>>(hbuf, Wt_hi, Wt_lo, tbuf);
        if (it == 2)
            gather_relu_kernel<<<ggrid, 256, 0, stream>>>(tbuf, offs, src_s, attr_s,
                                                          (bf16_t*)nullptr, out);
        else
            gather_relu_kernel<<<ggrid, 256, 0, stream>>>(tbuf, offs, src_s, attr_s,
                                                          hbuf, (float*)nullptr);
    }
}

// Round 6
// 815.293 us; speedup vs baseline: 2.9385x; 2.9385x over previous
//
#include <hip/hip_runtime.h>

#define N_NODES 20000
#define S_COLS  4096
#define E_EDGES 640000
#define D_DIM   256

typedef unsigned short bf16_t;
typedef __attribute__((ext_vector_type(8))) short short8;
typedef __attribute__((ext_vector_type(4))) float f32x4;

__device__ __forceinline__ float bf2f(bf16_t u) {
    union { unsigned int i; float f; } v; v.i = ((unsigned int)u) << 16; return v.f;
}
__device__ __forceinline__ bf16_t f2bf(float x) {   // round-to-nearest-even
    union { float f; unsigned int i; } v; v.f = x;
    unsigned int r = v.i + 0x7FFF + ((v.i >> 16) & 1);
    return (bf16_t)(r >> 16);
}
__device__ __forceinline__ float lo_bf(unsigned int u) {
    union { unsigned int i; float f; } v; v.i = u << 16; return v.f;
}
__device__ __forceinline__ float hi_bf(unsigned int u) {
    union { unsigned int i; float f; } v; v.i = u & 0xFFFF0000u; return v.f;
}
__device__ __forceinline__ unsigned int pack_bf(float a, float b) {
    return (unsigned int)f2bf(a) | ((unsigned int)f2bf(b) << 16);
}

// ---------------------------------------------------------------------------
// K1: h0[i] = (cnt*b2 + fsum @ w2) / max(cnt,1); fsum = 16-dim feature sum
// over nonzero column indices. Block-per-row (PROVEN round-3/4 version —
// the wave-per-row variant spilled to scratch: VGPR cap 64, 2.7 GB of
// scratch traffic, 1746 us. Keep per-thread state small.)
// ---------------------------------------------------------------------------
__global__ void h0_kernel(const float* __restrict__ init_m,
                          const float* __restrict__ w1, const float* __restrict__ b1,
                          const float* __restrict__ w2, const float* __restrict__ b2,
                          bf16_t* __restrict__ h) {
    __shared__ float w2s[16][256];
    __shared__ int   list[1024];
    __shared__ int   count;
    __shared__ float fred[4][16];
    __shared__ float ftot[16];
    int i = blockIdx.x;
    int t = threadIdx.x;

#pragma unroll
    for (int k = 0; k < 16; ++k) w2s[k][t] = w2[k * D_DIM + t];
    if (t == 0) count = 0;
    __syncthreads();

    const float4* rowp = (const float4*)(init_m + (size_t)i * S_COLS);
#pragma unroll
    for (int p = 0; p < 4; ++p) {
        int v4 = t + p * 256;
        float4 v = rowp[v4];
        int jbase = v4 * 4;
        if (v.x != 0.f) { int idx = atomicAdd(&count, 1); list[idx] = jbase;     }
        if (v.y != 0.f) { int idx = atomicAdd(&count, 1); list[idx] = jbase + 1; }
        if (v.z != 0.f) { int idx = atomicAdd(&count, 1); list[idx] = jbase + 2; }
        if (v.w != 0.f) { int idx = atomicAdd(&count, 1); list[idx] = jbase + 3; }
    }
    __syncthreads();
    int cnt = count;

    float lw1[16], lb1[16];
#pragma unroll
    for (int k = 0; k < 16; ++k) { lw1[k] = w1[k]; lb1[k] = b1[k]; }
    float f[16] = {};
    for (int q = t; q < cnt; q += 256) {
        float jf = (float)list[q];
#pragma unroll
        for (int k = 0; k < 16; ++k)
            f[k] += fmaxf(jf * lw1[k] + lb1[k], 0.f);
    }
#pragma unroll
    for (int k = 0; k < 16; ++k) {
#pragma unroll
        for (int off = 32; off > 0; off >>= 1)
            f[k] += __shfl_xor(f[k], off, 64);
    }
    int wave = t >> 6, lane = t & 63;
    if (lane == 0) {
#pragma unroll
        for (int k = 0; k < 16; ++k) fred[wave][k] = f[k];
    }
    __syncthreads();
    if (t < 16) ftot[t] = fred[0][t] + fred[1][t] + fred[2][t] + fred[3][t];
    __syncthreads();

    float cf = (float)cnt;
    float acc = cf * b2[t];
#pragma unroll
    for (int k = 0; k < 16; ++k) acc += ftot[k] * w2s[k][t];
    h[(size_t)i * D_DIM + t] = f2bf(acc / fmaxf(cf, 1.f));
}

// ---------------------------------------------------------------------------
// CSC build (counting sort by destination col)
// ---------------------------------------------------------------------------
__global__ void count_kernel(const int* __restrict__ eidx, int* __restrict__ cnt) {
    int e = blockIdx.x * 256 + threadIdx.x;
    if (e < E_EDGES) atomicAdd(&cnt[eidx[E_EDGES + e]], 1);
}

__global__ void scan_kernel(const int* __restrict__ cnt, int* __restrict__ offs,
                            int* __restrict__ cur) {
    __shared__ int sdata[1024];
    int t = threadIdx.x;
    int base = t * 20;
    int vals[20];
    int local = 0;
#pragma unroll
    for (int k = 0; k < 20; ++k) {
        int idx = base + k;
        int v = (idx < N_NODES) ? cnt[idx] : 0;
        vals[k] = local;
        local += v;
    }
    sdata[t] = local;
    __syncthreads();
    for (int off = 1; off < 1024; off <<= 1) {
        int v = (t >= off) ? sdata[t - off] : 0;
        __syncthreads();
        sdata[t] += v;
        __syncthreads();
    }
    int prefix = (t == 0) ? 0 : sdata[t - 1];
#pragma unroll
    for (int k = 0; k < 20; ++k) {
        int idx = base + k;
        if (idx < N_NODES) {
            int o = prefix + vals[k];
            offs[idx] = o;
            cur[idx]  = o;
        }
    }
    if (t == 1023) offs[N_NODES] = sdata[1023];
}

__global__ void fill_kernel(const int* __restrict__ eidx, const float* __restrict__ attr,
                            int* __restrict__ cur, int* __restrict__ src_s,
                            float* __restrict__ attr_s) {
    int e = blockIdx.x * 256 + threadIdx.x;
    if (e < E_EDGES) {
        int r = eidx[e];
        int c = eidx[E_EDGES + e];
        int pos = atomicAdd(&cur[c], 1);
        src_s[pos]  = r;
        attr_s[pos] = attr[e];
    }
}

// ---------------------------------------------------------------------------
// W preprocessing: transpose + fp32 -> bf16 hi/lo split
// ---------------------------------------------------------------------------
__global__ void wsplit_kernel(const float* __restrict__ W,
                              bf16_t* __restrict__ Wt_hi, bf16_t* __restrict__ Wt_lo) {
    int k = blockIdx.x;
    int n = threadIdx.x;
    float w = W[k * D_DIM + n];
    bf16_t hi = f2bf(w);
    bf16_t lo = f2bf(w - bf2f(hi));
    Wt_hi[n * D_DIM + k] = hi;
    Wt_lo[n * D_DIM + k] = lo;
}

// ---------------------------------------------------------------------------
// K3: t = h @ W, bf16 in/out, W = hi+lo planes (n-major). MFMA 16x16x32.
// ---------------------------------------------------------------------------
__global__ void gemm_mfma_kernel(const bf16_t* __restrict__ h,
                                 const bf16_t* __restrict__ Wt_hi,
                                 const bf16_t* __restrict__ Wt_lo,
                                 bf16_t* __restrict__ t) {
    int w    = threadIdx.x >> 6;
    int lane = threadIdx.x & 63;
    int quad = lane >> 4;
    int id16 = lane & 15;
    int bm   = blockIdx.x * 64 + w * 16;
    int bn   = blockIdx.y * 64;

    f32x4 acc[4];
#pragma unroll
    for (int nt = 0; nt < 4; ++nt) acc[nt] = (f32x4){0.f, 0.f, 0.f, 0.f};

    const bf16_t* arow = h + (size_t)(bm + id16) * D_DIM;
#pragma unroll
    for (int k0 = 0; k0 < 256; k0 += 32) {
        short8 a = *(const short8*)(arow + k0 + quad * 8);
#pragma unroll
        for (int nt = 0; nt < 4; ++nt) {
            const bf16_t* brow = Wt_hi + (size_t)(bn + nt * 16 + id16) * D_DIM + k0 + quad * 8;
            const bf16_t* lrow = Wt_lo + (size_t)(bn + nt * 16 + id16) * D_DIM + k0 + quad * 8;
            short8 bh = *(const short8*)brow;
            short8 bl = *(const short8*)lrow;
            acc[nt] = __builtin_amdgcn_mfma_f32_16x16x32_bf16(a, bh, acc[nt], 0, 0, 0);
            acc[nt] = __builtin_amdgcn_mfma_f32_16x16x32_bf16(a, bl, acc[nt], 0, 0, 0);
        }
    }
#pragma unroll
    for (int nt = 0; nt < 4; ++nt) {
#pragma unroll
        for (int r = 0; r < 4; ++r) {
            int m = bm + quad * 4 + r;
            if (m < N_NODES)
                t[(size_t)m * D_DIM + bn + nt * 16 + id16] = f2bf(acc[nt][r]);
        }
    }
}

// ---------------------------------------------------------------------------
// K2: h_next[c] = relu( sum_{e into c} t[src[e]] * attr[e] )
// One wave per dest; half-wave per edge, 16B loads. Edge count padded to a
// multiple of 16 -> 8 independent loads in flight per wave (padded slots:
// a=0, r=0 -> row-0 loads, L1-hot, zero contribution).
// ---------------------------------------------------------------------------
__global__ void gather_relu_kernel(const bf16_t* __restrict__ t,
                                   const int* __restrict__ offs,
                                   const int* __restrict__ src_s,
                                   const float* __restrict__ attr_s,
                                   bf16_t* __restrict__ hdst, float* __restrict__ fdst) {
    int wid  = (blockIdx.x * blockDim.x + threadIdx.x) >> 6;
    int lane = threadIdx.x & 63;
    if (wid >= N_NODES) return;
    int half = lane >> 5;
    int l32  = lane & 31;
    int e0 = offs[wid], e1 = offs[wid + 1];

    float acc[8] = {};
    for (int base = e0; base < e1; base += 64) {
        int n = e1 - base; if (n > 64) n = 64;
        int   r_l = 0; float a_l = 0.f;
        if (lane < n) { r_l = src_s[base + lane]; a_l = attr_s[base + lane]; }
        int nn = (n + 15) & ~15;            // pad to 8 pair-iterations
        for (int q = 0; q < nn; q += 16) {
#pragma unroll
            for (int u = 0; u < 8; ++u) {
                int   sl = q + 2 * u + half;
                int   r  = __shfl(r_l, sl, 64);
                float a  = __shfl(a_l, sl, 64);
                uint4 v  = ((const uint4*)(t + (size_t)r * D_DIM))[l32];
                acc[0] += lo_bf(v.x) * a;  acc[1] += hi_bf(v.x) * a;
                acc[2] += lo_bf(v.y) * a;  acc[3] += hi_bf(v.y) * a;
                acc[4] += lo_bf(v.z) * a;  acc[5] += hi_bf(v.z) * a;
                acc[6] += lo_bf(v.w) * a;  acc[7] += hi_bf(v.w) * a;
            }
        }
    }
#pragma unroll
    for (int i = 0; i < 8; ++i) acc[i] += __shfl_xor(acc[i], 32, 64);

    if (half == 0) {
#pragma unroll
        for (int i = 0; i < 8; ++i) acc[i] = fmaxf(acc[i], 0.f);
        if (hdst) {
            uint4 o;
            o.x = pack_bf(acc[0], acc[1]);
            o.y = pack_bf(acc[2], acc[3]);
            o.z = pack_bf(acc[4], acc[5]);
            o.w = pack_bf(acc[6], acc[7]);
            ((uint4*)(hdst + (size_t)wid * D_DIM))[l32] = o;
        } else {
            float4 o0 = { acc[0], acc[1], acc[2], acc[3] };
            float4 o1 = { acc[4], acc[5], acc[6], acc[7] };
            float* dst = fdst + (size_t)wid * D_DIM + l32 * 8;
            *(float4*)dst       = o0;
            *(float4*)(dst + 4) = o1;
        }
    }
}

extern "C" void kernel_launch(void* const* d_in, const int* in_sizes, int n_in,
                              void* d_out, int out_size, void* d_ws, size_t ws_size,
                              hipStream_t stream) {
    const float* init_m = (const float*)d_in[0];
    const int*   eidx   = (const int*)  d_in[1];
    const float* attr   = (const float*)d_in[2];
    const float* w1     = (const float*)d_in[3];
    const float* b1     = (const float*)d_in[4];
    const float* w2     = (const float*)d_in[5];
    const float* b2     = (const float*)d_in[6];
    const float* Wm     = (const float*)d_in[7];
    float* out = (float*)d_out;

    // Workspace layout (bytes). hbuf/tbuf have 16KB slack for the GEMM
    // m-overread (rows 20000..20031; poison is finite bf16).
    char* ws = (char*)d_ws;
    bf16_t* hbuf   = (bf16_t*)ws;                        // 10,240,000 (+16K slack)
    bf16_t* tbuf   = (bf16_t*)(ws + 10256384);           // 10,240,000 (+16K slack)
    bf16_t* Wt_hi  = (bf16_t*)(ws + 20512768);           // 131,072
    bf16_t* Wt_lo  = (bf16_t*)(ws + 20643840);           // 131,072
    int*    cnt    = (int*)   (ws + 20774912);           // 80,000
    int*    offs   = (int*)   (ws + 20854912);           // 80,004
    int*    cur    = (int*)   (ws + 20934928);           // 80,000
    int*    src_s  = (int*)   (ws + 21014928);           // 2,560,000
    float*  attr_s = (float*) (ws + 23574928);           // 2,560,000

    // --- CSC build ---
    hipMemsetAsync(cnt, 0, (size_t)N_NODES * sizeof(int), stream);
    count_kernel<<<(E_EDGES + 255) / 256, 256, 0, stream>>>(eidx, cnt);
    scan_kernel<<<1, 1024, 0, stream>>>(cnt, offs, cur);
    fill_kernel<<<(E_EDGES + 255) / 256, 256, 0, stream>>>(eidx, attr, cur, src_s, attr_s);

    // --- W transpose + hi/lo split ---
    wsplit_kernel<<<D_DIM, D_DIM, 0, stream>>>(Wm, Wt_hi, Wt_lo);

    // --- Projection: block-per-row (no spill) ---
    h0_kernel<<<N_NODES, 256, 0, stream>>>(init_m, w1, b1, w2, b2, hbuf);

    // --- 3x GCN layer: t = h@W (MFMA), then h' = relu(gather(t)) ---
    dim3 ggrid((N_NODES * 64 + 255) / 256);
    dim3 mgrid((N_NODES + 63) / 64, 4);
    for (int it = 0; it < 3; ++it) {
        gemm_mfma_kernel<<<mgrid, 256, 0, stream>>>(hbuf, Wt_hi, Wt_lo, tbuf);
        if (it == 2)
            gather_relu_kernel<<<ggrid, 256, 0, stream>>>(tbuf, offs, src_s, attr_s,
                                                          (bf16_t*)nullptr, out);
        else
            gather_relu_kernel<<<ggrid, 256, 0, stream>>>(tbuf, offs, src_s, attr_s,
                                                          hbuf, (float*)nullptr);
    }
}